// Round 8
// baseline (391.631 us; speedup 1.0000x reference)
//
#include <hip/hip_runtime.h>

// RegressorHybrid: per-edge 2x MLP (128->64->64->32->1, lrelu 0.01), E=2M, H=64.
// Round 14: 2-tile interleave, register-slimmed. R13's version spilled
// (WRITE 16->42MB, FETCH 184->253MB, VGPR capped 128): doubling
// Gcur+Gnxt+acc pushed unified demand past the 256 budget. The ILP theory
// was never tested - the spill masked it. Slimming:
// (a) NO Gnxt: Gcur is dead after layer 1 consumes B1 -> gather the next
//     pair directly into GcurA/B right after layer 1 (addrs from I2/I3,
//     lines warmed one iteration earlier; the L1-hit gather is covered by
//     layers 2-4 before next-iter use). -32 regs vs R13.
// (b) warm depth 1: WA/WB for pair p+2 issued at iter p, folded iter p+1
//     (one iter ~8K cyc >> 900cy fill). -8 regs vs R13.
// Peak audit: arch ~116 + 96 AGPR weights ~= 212 <= 256, margin ~44.
// Still per iteration: one w1f ds_read_b128 feeds TWO mfmas (per-tile LDS
// 16->8 b128, pipe floor 187K->94K cyc/CU) + two independent dep chains.
// Kept: w2f/w3f/w4/biases persistent AGPR, w1f 16KB LDS, eidx I2..I5
// rotating prefetch, stride-8 block pairing (m=(bid>>3)&1) for L2 warm
// dedup, warm law R1-R5 (one warm b128 covers the pair's lines, 1 fill
// each; consume gathers hit L1/L2), launch_bounds(256,2).
// MFMA layouts: A[m=lane&15][k=(lane>>4)*8+j], B[k=(lane>>4)*8+j][n=lane&15],
//               C/D[row=4*(lane>>4)+reg][col=lane&15].

typedef _Float16 half8  __attribute__((ext_vector_type(8)));
typedef _Float16 half4v __attribute__((ext_vector_type(4)));
typedef _Float16 half2v __attribute__((ext_vector_type(2)));
typedef float    float4v __attribute__((ext_vector_type(4)));

#define MLP_W_BYTES 28672          // w1f 16384 + w2f 8192 + w3f 4096
#define MLP_R_BYTES 12288          // w4f 2048 + b1f 4096 + b2f 4096 + b3f 2048
#define W1F 0
#define W2F 16384
#define W3F 24576
#define LDS_TOTAL   16384          // w1f only
#define WS_REST_OFF 57344
#define WS_X16_OFF  81920

__device__ __forceinline__ float lrelu(float x) { return fmaxf(x, 0.01f * x); }

__device__ __forceinline__ int uperm(int k) {
    return 16 * (2 * ((k >> 2) & 1) + ((k >> 5) & 1)) + 4 * ((k >> 3) & 3) + (k & 3);
}

// ---- pack one MLP's weights/biases into per-lane fragment order ----
__global__ void prep_frags(const float* __restrict__ w1, const float* __restrict__ b1,
                           const float* __restrict__ w2, const float* __restrict__ b2,
                           const float* __restrict__ w3, const float* __restrict__ b3,
                           const float* __restrict__ w4,
                           unsigned char* __restrict__ dstL,
                           unsigned char* __restrict__ dstR)
{
    int idx = blockIdx.x * blockDim.x + threadIdx.x;
    if (idx < 8192) {                      // w1f: [16 frags][64 lanes][8 f16]
        int L = (idx >> 3) & 63, j = idx & 7, f = idx >> 9;
        int q = L >> 4, mm = L & 15, t = f >> 2, s = f & 3;
        int k = 32 * s + 8 * q + j;
        ((_Float16*)(dstL + W1F))[idx] = (_Float16)w1[k * 64 + 16 * t + mm];
        return;
    }
    idx -= 8192;
    if (idx < 4096) {                      // w2f: [8][64][8]
        int L = (idx >> 3) & 63, j = idx & 7, f = idx >> 9;
        int q = L >> 4, mm = L & 15, t = f >> 1, s = f & 1;
        int u = uperm(32 * s + 8 * q + j);
        ((_Float16*)(dstL + W2F))[idx] = (_Float16)w2[u * 64 + 16 * t + mm];
        return;
    }
    idx -= 4096;
    if (idx < 2048) {                      // w3f: [4][64][8]
        int L = (idx >> 3) & 63, j = idx & 7, f = idx >> 9;
        int q = L >> 4, mm = L & 15, t = f >> 1, s = f & 1;
        int u = uperm(32 * s + 8 * q + j);
        ((_Float16*)(dstL + W3F))[idx] = (_Float16)w3[u * 32 + 16 * t + mm];
        return;
    }
    idx -= 2048;
    if (idx < 512) {                       // w4f
        int L = idx >> 3, j = idx & 7;
        int q = L >> 4, t = j >> 2, r = j & 3;
        ((float*)(dstR + 0))[idx] = w4[16 * t + 4 * q + r];
        return;
    }
    idx -= 512;
    if (idx < 1024) {                      // b1f
        int t = idx >> 8, L = (idx >> 2) & 63, r = idx & 3, q = L >> 4;
        ((float*)(dstR + 2048))[idx] = b1[16 * t + 4 * q + r];
        return;
    }
    idx -= 1024;
    if (idx < 1024) {                      // b2f
        int t = idx >> 8, L = (idx >> 2) & 63, r = idx & 3, q = L >> 4;
        ((float*)(dstR + 6144))[idx] = b2[16 * t + 4 * q + r];
        return;
    }
    idx -= 1024;
    if (idx < 512) {                       // b3f
        int t = idx >> 8, L = (idx >> 2) & 63, r = idx & 3, q = L >> 4;
        ((float*)(dstR + 10240))[idx] = b3[16 * t + 4 * q + r];
        return;
    }
}

// ---- convert node tables fp32 -> f16 ----
__global__ void prep_nodes(const float* __restrict__ xs, const float* __restrict__ xd,
                           _Float16* __restrict__ os, _Float16* __restrict__ od, int n4)
{
    int stride = gridDim.x * blockDim.x;
    for (int i = blockIdx.x * blockDim.x + threadIdx.x; i < n4; i += stride) {
        float4v a = ((const float4v*)xs)[i];
        float4v b = ((const float4v*)xd)[i];
        half4v ha, hb;
#pragma unroll
        for (int j = 0; j < 4; ++j) { ha[j] = (_Float16)a[j]; hb[j] = (_Float16)b[j]; }
        ((half4v*)os)[i] = ha;
        ((half4v*)od)[i] = hb;
    }
}

// packed repack: cvt_pkrtz (2 f32 -> 2 f16) then lrelu in f16 (pk mul+max).
__device__ __forceinline__ half2v cvt_pk(float a, float b) {
    return __builtin_bit_cast(half2v, __builtin_amdgcn_cvt_pkrtz(a, b));
}

__device__ __forceinline__ half8 repack2(float4v lo, float4v hi) {
    half8 r;
#pragma unroll
    for (int j = 0; j < 2; ++j) {
        half2v a = cvt_pk(lo[2 * j], lo[2 * j + 1]);
        half2v sa = a * (_Float16)0.01f;
        half2v ma = __builtin_elementwise_max(a, sa);
        r[2 * j] = ma[0]; r[2 * j + 1] = ma[1];
        half2v b = cvt_pk(hi[2 * j], hi[2 * j + 1]);
        half2v sb = b * (_Float16)0.01f;
        half2v mb = __builtin_elementwise_max(b, sb);
        r[4 + 2 * j] = mb[0]; r[4 + 2 * j + 1] = mb[1];
    }
    return r;
}

// eidx prefetch: (src,dst) node index pair for this lane's edge of a tile
__device__ __forceinline__ int2 load_eidx(const int* __restrict__ eidx,
                                          int nE, int tile, int n)
{
    int e = tile * 16 + n;
    int ec = e < nE ? e : nE - 1;
    return make_int2(eidx[ec], eidx[nE + ec]);
}

// R2-style consume gather from prefetched indices: lane (q,n) loads chunk q
// of edge n's 4 lines. Requests HIT L1/L2 (warmed an iteration earlier).
__device__ __forceinline__ void gather_tile(const _Float16* __restrict__ xs,
                                            const _Float16* __restrict__ xd,
                                            int2 sd, int q, int4* G)
{
    const char* rs = (const char*)(xs + (size_t)sd.x * 64);
    const char* rd = (const char*)(xd + (size_t)sd.y * 64);
    G[0] = *(const int4*)(rs + 16 * q);
    G[1] = *(const int4*)(rs + 64 + 16 * q);
    G[2] = *(const int4*)(rd + 16 * q);
    G[3] = *(const int4*)(rd + 64 + 16 * q);
}

// warm pass from prefetched indices: lane (c=q, n) touches line (edge n,
// combo c) once -> 64 distinct lines per instruction, one 64B fill each.
__device__ __forceinline__ int4 warm_tile(const _Float16* __restrict__ xs,
                                          const _Float16* __restrict__ xd,
                                          int2 sd, int c)
{
    int idx = (c & 2) ? sd.y : sd.x;
    const char* base = (const char*)(((c & 2) ? xd : xs) + (size_t)idx * 64);
    return *(const int4*)(base + (c & 1) * 64);
}

__global__ __launch_bounds__(256, 2)
void edge_mlp_mfma(const unsigned char* __restrict__ ws,
                   const _Float16* __restrict__ xs, const _Float16* __restrict__ xd,
                   const int* __restrict__ eidx,
                   const float* __restrict__ eb4p, const float* __restrict__ wb4p,
                   float* __restrict__ out, int nE, int ntiles)
{
    __shared__ unsigned char lds[LDS_TOTAL];
    // stride-8 pairing: blocks 16k+j and 16k+8+j (j<8) run the same tiles for
    // m=0/1 -> same XCD (%8 preserved) and adjacent dispatch -> L2 dedup.
    const int m = (blockIdx.x >> 3) & 1;
    const int bid = (blockIdx.x & 7) | ((blockIdx.x >> 4) << 3);
    const unsigned char* wbase = ws + m * MLP_W_BYTES;
    const unsigned char* rbase = ws + WS_REST_OFF + m * MLP_R_BYTES;
    {
        const uint4* s = (const uint4*)(wbase + W1F);
        uint4* d = (uint4*)lds;
        for (int i = threadIdx.x; i < LDS_TOTAL / 16; i += 256) d[i] = s[i];
    }

    const int lane = threadIdx.x & 63;
    const int q = lane >> 4, n = lane & 15;
    const int wid = (bid << 2) | (threadIdx.x >> 6);
    const int nwaves = gridDim.x << 1;     // (grid/2 blocks per MLP) * 4 waves
    const float b4s = m ? wb4p[0] : eb4p[0];
    float* __restrict__ outm = out + (m ? nE : 0);

    // ---- persistent register weights: w2f, w3f, w4, b1f, b2f, b3f ----
    half8 w2f[8], w3f[4];
#pragma unroll
    for (int f = 0; f < 8; ++f)
        w2f[f] = *(const half8*)(wbase + W2F + (f * 64 + lane) * 16);
#pragma unroll
    for (int f = 0; f < 4; ++f)
        w3f[f] = *(const half8*)(wbase + W3F + (f * 64 + lane) * 16);
    float4v w40 = *(const float4v*)(rbase + 0 + lane * 32);
    float4v w41 = *(const float4v*)(rbase + 0 + lane * 32 + 16);
    float4v b1f[4], b2f[4], b3f[2];
#pragma unroll
    for (int t = 0; t < 4; ++t)
        b1f[t] = *(const float4v*)(rbase + 2048 + (t * 64 + lane) * 16);
#pragma unroll
    for (int t = 0; t < 4; ++t)
        b2f[t] = *(const float4v*)(rbase + 6144 + (t * 64 + lane) * 16);
#pragma unroll
    for (int t = 0; t < 2; ++t)
        b3f[t] = *(const float4v*)(rbase + 10240 + (t * 64 + lane) * 16);

    __syncthreads();

    int4 GcurA[4], GcurB[4];
    int4 WA = {0,0,0,0}, WB = {0,0,0,0}, junk = {0,0,0,0};
    int2 I2 = {0,0}, I3 = {0,0}, I4 = {0,0}, I5 = {0,0};

    int tile = wid;
    if (tile < ntiles) {
        int2 I0 = load_eidx(eidx, nE, tile, n);
        int2 I1 = load_eidx(eidx, nE, tile + nwaves, n);
        I2 = load_eidx(eidx, nE, tile + 2 * nwaves, n);
        I3 = load_eidx(eidx, nE, tile + 3 * nwaves, n);
        I4 = load_eidx(eidx, nE, tile + 4 * nwaves, n);
        I5 = load_eidx(eidx, nE, tile + 5 * nwaves, n);
        // warm pair0, fold immediately (prologue only); gathers queue behind
        // the same-line fills and arrive warm.
        WA = warm_tile(xs, xd, I0, q);
        WB = warm_tile(xs, xd, I1, q);
        junk.x ^= WA.x ^ WB.x; junk.y ^= WA.y ^ WB.y;
        junk.z ^= WA.z ^ WB.z; junk.w ^= WA.w ^ WB.w;
        gather_tile(xs, xd, I0, q, GcurA);
        gather_tile(xs, xd, I1, q, GcurB);
        // warm pair1 (folded at iter0)
        WA = warm_tile(xs, xd, I2, q);
        WB = warm_tile(xs, xd, I3, q);
    }

#pragma unroll 1
    for (; tile < ntiles; tile += 2 * nwaves) {
        half8 B1A[4], B1B[4];
#pragma unroll
        for (int s = 0; s < 4; ++s) {
            B1A[s] = __builtin_bit_cast(half8, GcurA[s]);
            B1B[s] = __builtin_bit_cast(half8, GcurB[s]);
        }

        // ---- layer 1: 128 -> 64; one A-frag read feeds both tiles ----
        float4v accA[4], accB[4];
#pragma unroll
        for (int t = 0; t < 4; ++t) {
            accA[t] = b1f[t]; accB[t] = b1f[t];
#pragma unroll
            for (int s = 0; s < 4; ++s) {
                half8 A = *(const half8*)(lds + W1F + ((t * 4 + s) * 64 + lane) * 16);
                accA[t] = __builtin_amdgcn_mfma_f32_16x16x32_f16(A, B1A[s], accA[t], 0, 0, 0);
                accB[t] = __builtin_amdgcn_mfma_f32_16x16x32_f16(A, B1B[s], accB[t], 0, 0, 0);
            }
        }

        // Gcur is dead (B1 consumed): gather NEXT pair into it now.
        // Lines warmed one iteration ago -> L1/L2 hits; result not used
        // until next iteration -> covered by layers 2-4.
        gather_tile(xs, xd, I2, q, GcurA);
        gather_tile(xs, xd, I3, q, GcurB);

        // fold pair p+1's warms (issued last iter, long complete),
        // issue warms for pair p+2 from prefetched I4/I5.
        junk.x ^= WA.x ^ WB.x; junk.y ^= WA.y ^ WB.y;
        junk.z ^= WA.z ^ WB.z; junk.w ^= WA.w ^ WB.w;
        WA = warm_tile(xs, xd, I4, q);
        WB = warm_tile(xs, xd, I5, q);

        // rotate eidx pipeline; fetch for pair p+3
        I2 = I4; I3 = I5;
        I4 = load_eidx(eidx, nE, tile + 6 * nwaves, n);
        I5 = load_eidx(eidx, nE, tile + 7 * nwaves, n);

        // ---- layer 2: 64 -> 64 (A from AGPR regs) ----
        half8 B2A[2] = { repack2(accA[0], accA[2]), repack2(accA[1], accA[3]) };
        half8 B2B[2] = { repack2(accB[0], accB[2]), repack2(accB[1], accB[3]) };
        float4v acc2A[4], acc2B[4];
#pragma unroll
        for (int t = 0; t < 4; ++t) {
            acc2A[t] = b2f[t]; acc2B[t] = b2f[t];
#pragma unroll
            for (int s = 0; s < 2; ++s) {
                acc2A[t] = __builtin_amdgcn_mfma_f32_16x16x32_f16(w2f[t * 2 + s], B2A[s], acc2A[t], 0, 0, 0);
                acc2B[t] = __builtin_amdgcn_mfma_f32_16x16x32_f16(w2f[t * 2 + s], B2B[s], acc2B[t], 0, 0, 0);
            }
        }
        // ---- layer 3: 64 -> 32 (A from AGPR regs) ----
        half8 B3A[2] = { repack2(acc2A[0], acc2A[2]), repack2(acc2A[1], acc2A[3]) };
        half8 B3B[2] = { repack2(acc2B[0], acc2B[2]), repack2(acc2B[1], acc2B[3]) };
        float4v acc3A[2], acc3B[2];
#pragma unroll
        for (int t = 0; t < 2; ++t) {
            acc3A[t] = b3f[t]; acc3B[t] = b3f[t];
#pragma unroll
            for (int s = 0; s < 2; ++s) {
                acc3A[t] = __builtin_amdgcn_mfma_f32_16x16x32_f16(w3f[t * 2 + s], B3A[s], acc3A[t], 0, 0, 0);
                acc3B[t] = __builtin_amdgcn_mfma_f32_16x16x32_f16(w3f[t * 2 + s], B3B[s], acc3B[t], 0, 0, 0);
            }
        }
        // ---- layer 4: 32 -> 1 (w4 in regs) ----
        float oA = 0.f, oB = 0.f;
#pragma unroll
        for (int r = 0; r < 4; ++r) {
            oA = fmaf(lrelu(acc3A[0][r]), w40[r], oA);
            oB = fmaf(lrelu(acc3B[0][r]), w40[r], oB);
        }
#pragma unroll
        for (int r = 0; r < 4; ++r) {
            oA = fmaf(lrelu(acc3A[1][r]), w41[r], oA);
            oB = fmaf(lrelu(acc3B[1][r]), w41[r], oB);
        }
        oA += __shfl_xor(oA, 16, 64);
        oA += __shfl_xor(oA, 32, 64);
        oB += __shfl_xor(oB, 16, 64);
        oB += __shfl_xor(oB, 32, 64);

        if (q == 0) {
            int eA = tile * 16 + n;
            int eB = (tile + nwaves) * 16 + n;
            if (eA < nE) outm[eA] = oA + b4s;
            if (eB < nE) outm[eB] = oB + b4s;
        }
    }

    // consume warm registers (never-taken, data-dependent guard defeats DCE)
    junk.x ^= WA.x ^ WB.x;
    junk.y ^= WA.y ^ WB.y;
    junk.z ^= WA.z ^ WB.z;
    junk.w ^= WA.w ^ WB.w;
    if (nE < 0 && (junk.x | junk.y | junk.z | junk.w) != 0)
        out[0] = -1.0f;
}

extern "C" void kernel_launch(void* const* d_in, const int* in_sizes, int n_in,
                              void* d_out, int out_size, void* d_ws, size_t ws_size,
                              hipStream_t stream)
{
    const float* x_src = (const float*)d_in[0];
    const float* x_dst = (const float*)d_in[1];
    const int*   eidx  = (const int*)d_in[2];
    const float* ew1 = (const float*)d_in[3];
    const float* eb1 = (const float*)d_in[4];
    const float* ww1 = (const float*)d_in[5];
    const float* wb1 = (const float*)d_in[6];
    const float* ew2 = (const float*)d_in[7];
    const float* eb2 = (const float*)d_in[8];
    const float* ww2 = (const float*)d_in[9];
    const float* wb2 = (const float*)d_in[10];
    const float* ew3 = (const float*)d_in[11];
    const float* eb3 = (const float*)d_in[12];
    const float* ww3 = (const float*)d_in[13];
    const float* wb3 = (const float*)d_in[14];
    const float* ew4 = (const float*)d_in[15];
    const float* eb4 = (const float*)d_in[16];
    const float* ww4 = (const float*)d_in[17];
    const float* wb4 = (const float*)d_in[18];
    float* out = (float*)d_out;

    const int nE = in_sizes[2] / 2;          // 2 x E index array (int32)
    const int nNodeElems = in_sizes[0];      // N_NODES * 64
    unsigned char* ws = (unsigned char*)d_ws;
    _Float16* xs16 = (_Float16*)(ws + WS_X16_OFF);
    _Float16* xd16 = xs16 + nNodeElems;

    prep_frags<<<68, 256, 0, stream>>>(ew1, eb1, ew2, eb2, ew3, eb3, ew4,
                                       ws, ws + WS_REST_OFF);
    prep_frags<<<68, 256, 0, stream>>>(ww1, wb1, ww2, wb2, ww3, wb3, ww4,
                                       ws + MLP_W_BYTES, ws + WS_REST_OFF + MLP_R_BYTES);
    prep_nodes<<<1024, 256, 0, stream>>>(x_src, x_dst, xs16, xd16, nNodeElems / 4);

    const int ntiles = (nE + 15) / 16;
    edge_mlp_mfma<<<1024, 256, 0, stream>>>(ws, xs16, xd16, eidx, eb4, wb4,
                                            out, nE, ntiles);
}

// Round 10
// 284.815 us; speedup vs baseline: 1.3750x; 1.3750x over previous
//
#include <hip/hip_runtime.h>

// RegressorHybrid: per-edge 2x MLP (128->64->64->32->1, lrelu 0.01), E=2M, H=64.
// Round 16 = Round 15 resubmitted verbatim (R15 hit an infra failure:
// "MI355X container failed twice"; no counters, theory untested).
// R15: revert to R12 (205us, clean) + in-place gather + setprio.
// R13/R14 (2-tile interleave) both spilled at VGPR_Count=128 exactly despite
// audits of 212-240 "fitting" 256: the arch/AGPR SPLIT heuristic is the
// binding constraint - doubled MFMA accumulators (+72 regs wanting the AGPR
// side next to 96 weight AGPRs) overflow whichever 128/128 split the
// allocator picks. Lesson: at this weight residency, 2-tile is infeasible;
// single-tile R12 structure is the platform.
// Tweak 1 (from R14, untested alone): Gcur is dead once B1 is cast -> gather
// tile t+1 into Gcur right after layer 1 (no Gnxt: -16 arch regs; prefetch
// cover = layers 2-4 ~2K cyc >> 120cy L1 hit).
// Tweak 2 (T5): s_setprio(1) around compute clusters, 0 around the
// gather/warm/eidx issue block. 2 waves/SIMD drift out of phase
// (independent, not barrier-locked = m191 attn regime, +4-7% there):
// scheduler prefers the compute-phase wave while the other issues memory.
// Kept from R12: w2f/w3f/w4/biases in ~96 persistent AGPRs, w1f 16KB LDS
// (16 ds_read_b128/tile), eidx I1-I3 rotating prefetch (gather addrs in
// regs), packed repack via cvt_pkrtz + pk f16 ops, stride-8 block pairing
// (m=(bid>>3)&1) for L2 warm dedup, warm law R1-R5 (one warm b128 covers
// the tile's 64 lines, 1 fill each; consume gathers hit L1/L2),
// launch_bounds(256,2) (honest allocation, no occupancy request).
// MFMA layouts: A[m=lane&15][k=(lane>>4)*8+j], B[k=(lane>>4)*8+j][n=lane&15],
//               C/D[row=4*(lane>>4)+reg][col=lane&15].

typedef _Float16 half8  __attribute__((ext_vector_type(8)));
typedef _Float16 half4v __attribute__((ext_vector_type(4)));
typedef _Float16 half2v __attribute__((ext_vector_type(2)));
typedef float    float4v __attribute__((ext_vector_type(4)));

#define MLP_W_BYTES 28672          // w1f 16384 + w2f 8192 + w3f 4096
#define MLP_R_BYTES 12288          // w4f 2048 + b1f 4096 + b2f 4096 + b3f 2048
#define W1F 0
#define W2F 16384
#define W3F 24576
#define LDS_TOTAL   16384          // w1f only
#define WS_REST_OFF 57344
#define WS_X16_OFF  81920

__device__ __forceinline__ float lrelu(float x) { return fmaxf(x, 0.01f * x); }

__device__ __forceinline__ int uperm(int k) {
    return 16 * (2 * ((k >> 2) & 1) + ((k >> 5) & 1)) + 4 * ((k >> 3) & 3) + (k & 3);
}

// ---- pack one MLP's weights/biases into per-lane fragment order ----
__global__ void prep_frags(const float* __restrict__ w1, const float* __restrict__ b1,
                           const float* __restrict__ w2, const float* __restrict__ b2,
                           const float* __restrict__ w3, const float* __restrict__ b3,
                           const float* __restrict__ w4,
                           unsigned char* __restrict__ dstL,
                           unsigned char* __restrict__ dstR)
{
    int idx = blockIdx.x * blockDim.x + threadIdx.x;
    if (idx < 8192) {                      // w1f: [16 frags][64 lanes][8 f16]
        int L = (idx >> 3) & 63, j = idx & 7, f = idx >> 9;
        int q = L >> 4, mm = L & 15, t = f >> 2, s = f & 3;
        int k = 32 * s + 8 * q + j;
        ((_Float16*)(dstL + W1F))[idx] = (_Float16)w1[k * 64 + 16 * t + mm];
        return;
    }
    idx -= 8192;
    if (idx < 4096) {                      // w2f: [8][64][8]
        int L = (idx >> 3) & 63, j = idx & 7, f = idx >> 9;
        int q = L >> 4, mm = L & 15, t = f >> 1, s = f & 1;
        int u = uperm(32 * s + 8 * q + j);
        ((_Float16*)(dstL + W2F))[idx] = (_Float16)w2[u * 64 + 16 * t + mm];
        return;
    }
    idx -= 4096;
    if (idx < 2048) {                      // w3f: [4][64][8]
        int L = (idx >> 3) & 63, j = idx & 7, f = idx >> 9;
        int q = L >> 4, mm = L & 15, t = f >> 1, s = f & 1;
        int u = uperm(32 * s + 8 * q + j);
        ((_Float16*)(dstL + W3F))[idx] = (_Float16)w3[u * 32 + 16 * t + mm];
        return;
    }
    idx -= 2048;
    if (idx < 512) {                       // w4f
        int L = idx >> 3, j = idx & 7;
        int q = L >> 4, t = j >> 2, r = j & 3;
        ((float*)(dstR + 0))[idx] = w4[16 * t + 4 * q + r];
        return;
    }
    idx -= 512;
    if (idx < 1024) {                      // b1f
        int t = idx >> 8, L = (idx >> 2) & 63, r = idx & 3, q = L >> 4;
        ((float*)(dstR + 2048))[idx] = b1[16 * t + 4 * q + r];
        return;
    }
    idx -= 1024;
    if (idx < 1024) {                      // b2f
        int t = idx >> 8, L = (idx >> 2) & 63, r = idx & 3, q = L >> 4;
        ((float*)(dstR + 6144))[idx] = b2[16 * t + 4 * q + r];
        return;
    }
    idx -= 1024;
    if (idx < 512) {                       // b3f
        int t = idx >> 8, L = (idx >> 2) & 63, r = idx & 3, q = L >> 4;
        ((float*)(dstR + 10240))[idx] = b3[16 * t + 4 * q + r];
        return;
    }
}

// ---- convert node tables fp32 -> f16 ----
__global__ void prep_nodes(const float* __restrict__ xs, const float* __restrict__ xd,
                           _Float16* __restrict__ os, _Float16* __restrict__ od, int n4)
{
    int stride = gridDim.x * blockDim.x;
    for (int i = blockIdx.x * blockDim.x + threadIdx.x; i < n4; i += stride) {
        float4v a = ((const float4v*)xs)[i];
        float4v b = ((const float4v*)xd)[i];
        half4v ha, hb;
#pragma unroll
        for (int j = 0; j < 4; ++j) { ha[j] = (_Float16)a[j]; hb[j] = (_Float16)b[j]; }
        ((half4v*)os)[i] = ha;
        ((half4v*)od)[i] = hb;
    }
}

// packed repack: cvt_pkrtz (2 f32 -> 2 f16) then lrelu in f16 (pk mul+max).
__device__ __forceinline__ half2v cvt_pk(float a, float b) {
    return __builtin_bit_cast(half2v, __builtin_amdgcn_cvt_pkrtz(a, b));
}

__device__ __forceinline__ half8 repack2(float4v lo, float4v hi) {
    half8 r;
#pragma unroll
    for (int j = 0; j < 2; ++j) {
        half2v a = cvt_pk(lo[2 * j], lo[2 * j + 1]);
        half2v sa = a * (_Float16)0.01f;
        half2v ma = __builtin_elementwise_max(a, sa);
        r[2 * j] = ma[0]; r[2 * j + 1] = ma[1];
        half2v b = cvt_pk(hi[2 * j], hi[2 * j + 1]);
        half2v sb = b * (_Float16)0.01f;
        half2v mb = __builtin_elementwise_max(b, sb);
        r[4 + 2 * j] = mb[0]; r[4 + 2 * j + 1] = mb[1];
    }
    return r;
}

// eidx prefetch: (src,dst) node index pair for this lane's edge of a tile
__device__ __forceinline__ int2 load_eidx(const int* __restrict__ eidx,
                                          int nE, int tile, int n)
{
    int e = tile * 16 + n;
    int ec = e < nE ? e : nE - 1;
    return make_int2(eidx[ec], eidx[nE + ec]);
}

// R2-style consume gather from prefetched indices: lane (q,n) loads chunk q
// of edge n's 4 lines. Requests HIT L1/L2 (warmed iterations earlier).
__device__ __forceinline__ void gather_tile(const _Float16* __restrict__ xs,
                                            const _Float16* __restrict__ xd,
                                            int2 sd, int q, int4* G)
{
    const char* rs = (const char*)(xs + (size_t)sd.x * 64);
    const char* rd = (const char*)(xd + (size_t)sd.y * 64);
    G[0] = *(const int4*)(rs + 16 * q);
    G[1] = *(const int4*)(rs + 64 + 16 * q);
    G[2] = *(const int4*)(rd + 16 * q);
    G[3] = *(const int4*)(rd + 64 + 16 * q);
}

// warm pass from prefetched indices: lane (c=q, n) touches line (edge n,
// combo c) once -> 64 distinct lines per instruction, one 64B fill each.
__device__ __forceinline__ int4 warm_tile(const _Float16* __restrict__ xs,
                                          const _Float16* __restrict__ xd,
                                          int2 sd, int c)
{
    int idx = (c & 2) ? sd.y : sd.x;
    const char* base = (const char*)(((c & 2) ? xd : xs) + (size_t)idx * 64);
    return *(const int4*)(base + (c & 1) * 64);
}

__global__ __launch_bounds__(256, 2)
void edge_mlp_mfma(const unsigned char* __restrict__ ws,
                   const _Float16* __restrict__ xs, const _Float16* __restrict__ xd,
                   const int* __restrict__ eidx,
                   const float* __restrict__ eb4p, const float* __restrict__ wb4p,
                   float* __restrict__ out, int nE, int ntiles)
{
    __shared__ unsigned char lds[LDS_TOTAL];
    // stride-8 pairing: blocks 16k+j and 16k+8+j (j<8) run the same tiles for
    // m=0/1 -> same XCD (%8 preserved) and adjacent dispatch -> L2 dedup.
    const int m = (blockIdx.x >> 3) & 1;
    const int bid = (blockIdx.x & 7) | ((blockIdx.x >> 4) << 3);
    const unsigned char* wbase = ws + m * MLP_W_BYTES;
    const unsigned char* rbase = ws + WS_REST_OFF + m * MLP_R_BYTES;
    {
        const uint4* s = (const uint4*)(wbase + W1F);
        uint4* d = (uint4*)lds;
        for (int i = threadIdx.x; i < LDS_TOTAL / 16; i += 256) d[i] = s[i];
    }

    const int lane = threadIdx.x & 63;
    const int q = lane >> 4, n = lane & 15;
    const int wid = (bid << 2) | (threadIdx.x >> 6);
    const int nwaves = gridDim.x << 1;     // (grid/2 blocks per MLP) * 4 waves
    const float b4s = m ? wb4p[0] : eb4p[0];
    float* __restrict__ outm = out + (m ? nE : 0);

    // ---- persistent register weights: w2f, w3f, w4, b1f, b2f, b3f ----
    half8 w2f[8], w3f[4];
#pragma unroll
    for (int f = 0; f < 8; ++f)
        w2f[f] = *(const half8*)(wbase + W2F + (f * 64 + lane) * 16);
#pragma unroll
    for (int f = 0; f < 4; ++f)
        w3f[f] = *(const half8*)(wbase + W3F + (f * 64 + lane) * 16);
    float4v w40 = *(const float4v*)(rbase + 0 + lane * 32);
    float4v w41 = *(const float4v*)(rbase + 0 + lane * 32 + 16);
    float4v b1f[4], b2f[4], b3f[2];
#pragma unroll
    for (int t = 0; t < 4; ++t)
        b1f[t] = *(const float4v*)(rbase + 2048 + (t * 64 + lane) * 16);
#pragma unroll
    for (int t = 0; t < 4; ++t)
        b2f[t] = *(const float4v*)(rbase + 6144 + (t * 64 + lane) * 16);
#pragma unroll
    for (int t = 0; t < 2; ++t)
        b3f[t] = *(const float4v*)(rbase + 10240 + (t * 64 + lane) * 16);

    __syncthreads();

    int4 Gcur[4];
    int4 W0 = {0,0,0,0}, W1 = {0,0,0,0}, W2 = {0,0,0,0}, junk = {0,0,0,0};
    int2 I1 = {0,0}, I2 = {0,0}, I3 = {0,0};

    int tile = wid;
    if (tile < ntiles) {
        int t1 = tile + nwaves;     if (t1 >= ntiles) t1 = ntiles - 1;
        int t2 = tile + 2 * nwaves; if (t2 >= ntiles) t2 = ntiles - 1;
        int t3 = tile + 3 * nwaves; if (t3 >= ntiles) t3 = ntiles - 1;
        int2 I0 = load_eidx(eidx, nE, tile, n);
        I1 = load_eidx(eidx, nE, t1, n);
        I2 = load_eidx(eidx, nE, t2, n);
        I3 = load_eidx(eidx, nE, t3, n);
        W0 = warm_tile(xs, xd, I0, q);
        W1 = warm_tile(xs, xd, I1, q);
        W2 = warm_tile(xs, xd, I2, q);
        gather_tile(xs, xd, I0, q, Gcur);
    }

#pragma unroll 1
    for (; tile < ntiles; tile += nwaves) {
        half8 B1[4];
#pragma unroll
        for (int s = 0; s < 4; ++s) B1[s] = __builtin_bit_cast(half8, Gcur[s]);

        // ---- layer 1: 128 -> 64 (bias C-init from regs, A from LDS) ----
        __builtin_amdgcn_s_setprio(1);
        float4v acc[4];
#pragma unroll
        for (int t = 0; t < 4; ++t) {
            acc[t] = b1f[t];
#pragma unroll
            for (int s = 0; s < 4; ++s) {
                half8 A = *(const half8*)(lds + W1F + ((t * 4 + s) * 64 + lane) * 16);
                acc[t] = __builtin_amdgcn_mfma_f32_16x16x32_f16(A, B1[s], acc[t], 0, 0, 0);
            }
        }
        __builtin_amdgcn_s_setprio(0);

        // memory-issue block (low prio: let the other wave's compute run):
        // Gcur is dead (B1 consumed) -> gather NEXT tile into it in place.
        // Lines warmed 3 iterations ago -> L1/L2 hits; result consumed at
        // next loop top -> covered by layers 2-4 (~2K cyc >> 120cy).
        gather_tile(xs, xd, I1, q, Gcur);

        // fold oldest warm (3 iters old -> complete), rotate, issue new warm
        junk.x ^= W0.x; junk.y ^= W0.y; junk.z ^= W0.z; junk.w ^= W0.w;
        W0 = W1; W1 = W2;
        W2 = warm_tile(xs, xd, I3, q);

        // rotate eidx pipeline; issue fetch for tile+4nw
        {
            int t4 = tile + 4 * nwaves; if (t4 >= ntiles) t4 = ntiles - 1;
            I1 = I2; I2 = I3;
            I3 = load_eidx(eidx, nE, t4, n);
        }

        // ---- layers 2-4 (A from AGPR regs; high prio) ----
        __builtin_amdgcn_s_setprio(1);
        half8 B2[2] = { repack2(acc[0], acc[2]), repack2(acc[1], acc[3]) };
        float4v acc2[4];
#pragma unroll
        for (int t = 0; t < 4; ++t) {
            acc2[t] = b2f[t];
#pragma unroll
            for (int s = 0; s < 2; ++s)
                acc2[t] = __builtin_amdgcn_mfma_f32_16x16x32_f16(w2f[t * 2 + s], B2[s], acc2[t], 0, 0, 0);
        }
        half8 B3[2] = { repack2(acc2[0], acc2[2]), repack2(acc2[1], acc2[3]) };
        float4v acc3[2];
#pragma unroll
        for (int t = 0; t < 2; ++t) {
            acc3[t] = b3f[t];
#pragma unroll
            for (int s = 0; s < 2; ++s)
                acc3[t] = __builtin_amdgcn_mfma_f32_16x16x32_f16(w3f[t * 2 + s], B3[s], acc3[t], 0, 0, 0);
        }
        float o = 0.f;
#pragma unroll
        for (int r = 0; r < 4; ++r) o = fmaf(lrelu(acc3[0][r]), w40[r], o);
#pragma unroll
        for (int r = 0; r < 4; ++r) o = fmaf(lrelu(acc3[1][r]), w41[r], o);
        o += __shfl_xor(o, 16, 64);
        o += __shfl_xor(o, 32, 64);
        __builtin_amdgcn_s_setprio(0);

        int e = tile * 16 + n;
        if (q == 0 && e < nE)
            outm[e] = o + b4s;
    }

    // consume warm registers (never-taken, data-dependent guard defeats DCE)
    junk.x ^= W0.x ^ W1.x ^ W2.x;
    junk.y ^= W0.y ^ W1.y ^ W2.y;
    junk.z ^= W0.z ^ W1.z ^ W2.z;
    junk.w ^= W0.w ^ W1.w ^ W2.w;
    if (nE < 0 && (junk.x | junk.y | junk.z | junk.w) != 0)
        out[0] = -1.0f;
}

extern "C" void kernel_launch(void* const* d_in, const int* in_sizes, int n_in,
                              void* d_out, int out_size, void* d_ws, size_t ws_size,
                              hipStream_t stream)
{
    const float* x_src = (const float*)d_in[0];
    const float* x_dst = (const float*)d_in[1];
    const int*   eidx  = (const int*)d_in[2];
    const float* ew1 = (const float*)d_in[3];
    const float* eb1 = (const float*)d_in[4];
    const float* ww1 = (const float*)d_in[5];
    const float* wb1 = (const float*)d_in[6];
    const float* ew2 = (const float*)d_in[7];
    const float* eb2 = (const float*)d_in[8];
    const float* ww2 = (const float*)d_in[9];
    const float* wb2 = (const float*)d_in[10];
    const float* ew3 = (const float*)d_in[11];
    const float* eb3 = (const float*)d_in[12];
    const float* ww3 = (const float*)d_in[13];
    const float* wb3 = (const float*)d_in[14];
    const float* ew4 = (const float*)d_in[15];
    const float* eb4 = (const float*)d_in[16];
    const float* ww4 = (const float*)d_in[17];
    const float* wb4 = (const float*)d_in[18];
    float* out = (float*)d_out;

    const int nE = in_sizes[2] / 2;          // 2 x E index array (int32)
    const int nNodeElems = in_sizes[0];      // N_NODES * 64
    unsigned char* ws = (unsigned char*)d_ws;
    _Float16* xs16 = (_Float16*)(ws + WS_X16_OFF);
    _Float16* xd16 = xs16 + nNodeElems;

    prep_frags<<<68, 256, 0, stream>>>(ew1, eb1, ew2, eb2, ew3, eb3, ew4,
                                       ws, ws + WS_REST_OFF);
    prep_frags<<<68, 256, 0, stream>>>(ww1, wb1, ww2, wb2, ww3, wb3, ww4,
                                       ws + MLP_W_BYTES, ws + WS_REST_OFF + MLP_R_BYTES);
    prep_nodes<<<1024, 256, 0, stream>>>(x_src, x_dst, xs16, xd16, nNodeElems / 4);

    const int ntiles = (nE + 15) / 16;
    edge_mlp_mfma<<<1024, 256, 0, stream>>>(ws, xs16, xd16, eidx, eb4, wb4,
                                            out, nE, ntiles);
}

// Round 11
// 284.799 us; speedup vs baseline: 1.3751x; 1.0001x over previous
//
#include <hip/hip_runtime.h>

// RegressorHybrid: per-edge 2x MLP (128->64->64->32->1, lrelu 0.01), E=2M, H=64.
// Round 17: w1 half-AGPR. R16 (in-place gather + setprio, 196us clean):
// LDS-pipe = 16 ds_read_b128/tile x 12cyc x 977 tile-inst/CU ~= 187K cyc =
// 40% of the 470K-cyc runtime - tallest pole (VALU 35%, MFMA 25%, HBM 13%).
// Fix: move 8 of 16 w1 frags (s=0,1 per t) into 32 persistent AGPRs next to
// the 96 weight AGPRs -> AGPR 128 + arch 120 = 248 <= 256 unified. Unlike
// R13/R14's spill-chase (arch-side TRANSIENT doubling), this adds only
// persistent AGPRs; arch demand unchanged -> low spill risk.
// (a) per-tile LDS 16->8 b128: CU LDS-pipe floor 187K->94K cyc (40%->20%);
// (b) each acc[t] chain STARTS with 2 AGPR MFMAs (no lgkmcnt) -> the s=2,3
//     LDS reads hide behind them. s-order preserved -> numerics identical.
// Kept from R16: single-tile R12 platform (2-tile infeasible: R13/R14),
// in-place gather (Gcur dead after B1 cast -> gather t+1 into it after
// layer 1), setprio(1) on compute / 0 on memory-issue block, w2f/w3f/w4/
// biases in 96 AGPRs, eidx I1-I3 rotating prefetch, packed cvt_pkrtz
// repack, stride-8 block pairing (m=(bid>>3)&1) for L2 warm dedup, warm
// law R1-R5 (one warm b128 covers the tile's 64 lines; consume gathers
// hit L1/L2; FETCH 185MB = raw), launch_bounds(256,2).
// MFMA layouts: A[m=lane&15][k=(lane>>4)*8+j], B[k=(lane>>4)*8+j][n=lane&15],
//               C/D[row=4*(lane>>4)+reg][col=lane&15].

typedef _Float16 half8  __attribute__((ext_vector_type(8)));
typedef _Float16 half4v __attribute__((ext_vector_type(4)));
typedef _Float16 half2v __attribute__((ext_vector_type(2)));
typedef float    float4v __attribute__((ext_vector_type(4)));

#define MLP_W_BYTES 28672          // w1f 16384 + w2f 8192 + w3f 4096
#define MLP_R_BYTES 12288          // w4f 2048 + b1f 4096 + b2f 4096 + b3f 2048
#define W1F 0
#define W2F 16384
#define W3F 24576
#define LDS_TOTAL   16384          // w1f only (s=2,3 half is what's read)
#define WS_REST_OFF 57344
#define WS_X16_OFF  81920

__device__ __forceinline__ float lrelu(float x) { return fmaxf(x, 0.01f * x); }

__device__ __forceinline__ int uperm(int k) {
    return 16 * (2 * ((k >> 2) & 1) + ((k >> 5) & 1)) + 4 * ((k >> 3) & 3) + (k & 3);
}

// ---- pack one MLP's weights/biases into per-lane fragment order ----
__global__ void prep_frags(const float* __restrict__ w1, const float* __restrict__ b1,
                           const float* __restrict__ w2, const float* __restrict__ b2,
                           const float* __restrict__ w3, const float* __restrict__ b3,
                           const float* __restrict__ w4,
                           unsigned char* __restrict__ dstL,
                           unsigned char* __restrict__ dstR)
{
    int idx = blockIdx.x * blockDim.x + threadIdx.x;
    if (idx < 8192) {                      // w1f: [16 frags][64 lanes][8 f16]
        int L = (idx >> 3) & 63, j = idx & 7, f = idx >> 9;
        int q = L >> 4, mm = L & 15, t = f >> 2, s = f & 3;
        int k = 32 * s + 8 * q + j;
        ((_Float16*)(dstL + W1F))[idx] = (_Float16)w1[k * 64 + 16 * t + mm];
        return;
    }
    idx -= 8192;
    if (idx < 4096) {                      // w2f: [8][64][8]
        int L = (idx >> 3) & 63, j = idx & 7, f = idx >> 9;
        int q = L >> 4, mm = L & 15, t = f >> 1, s = f & 1;
        int u = uperm(32 * s + 8 * q + j);
        ((_Float16*)(dstL + W2F))[idx] = (_Float16)w2[u * 64 + 16 * t + mm];
        return;
    }
    idx -= 4096;
    if (idx < 2048) {                      // w3f: [4][64][8]
        int L = (idx >> 3) & 63, j = idx & 7, f = idx >> 9;
        int q = L >> 4, mm = L & 15, t = f >> 1, s = f & 1;
        int u = uperm(32 * s + 8 * q + j);
        ((_Float16*)(dstL + W3F))[idx] = (_Float16)w3[u * 32 + 16 * t + mm];
        return;
    }
    idx -= 2048;
    if (idx < 512) {                       // w4f
        int L = idx >> 3, j = idx & 7;
        int q = L >> 4, t = j >> 2, r = j & 3;
        ((float*)(dstR + 0))[idx] = w4[16 * t + 4 * q + r];
        return;
    }
    idx -= 512;
    if (idx < 1024) {                      // b1f
        int t = idx >> 8, L = (idx >> 2) & 63, r = idx & 3, q = L >> 4;
        ((float*)(dstR + 2048))[idx] = b1[16 * t + 4 * q + r];
        return;
    }
    idx -= 1024;
    if (idx < 1024) {                      // b2f
        int t = idx >> 8, L = (idx >> 2) & 63, r = idx & 3, q = L >> 4;
        ((float*)(dstR + 6144))[idx] = b2[16 * t + 4 * q + r];
        return;
    }
    idx -= 1024;
    if (idx < 512) {                       // b3f
        int t = idx >> 8, L = (idx >> 2) & 63, r = idx & 3, q = L >> 4;
        ((float*)(dstR + 10240))[idx] = b3[16 * t + 4 * q + r];
        return;
    }
}

// ---- convert node tables fp32 -> f16 ----
__global__ void prep_nodes(const float* __restrict__ xs, const float* __restrict__ xd,
                           _Float16* __restrict__ os, _Float16* __restrict__ od, int n4)
{
    int stride = gridDim.x * blockDim.x;
    for (int i = blockIdx.x * blockDim.x + threadIdx.x; i < n4; i += stride) {
        float4v a = ((const float4v*)xs)[i];
        float4v b = ((const float4v*)xd)[i];
        half4v ha, hb;
#pragma unroll
        for (int j = 0; j < 4; ++j) { ha[j] = (_Float16)a[j]; hb[j] = (_Float16)b[j]; }
        ((half4v*)os)[i] = ha;
        ((half4v*)od)[i] = hb;
    }
}

// packed repack: cvt_pkrtz (2 f32 -> 2 f16) then lrelu in f16 (pk mul+max).
__device__ __forceinline__ half2v cvt_pk(float a, float b) {
    return __builtin_bit_cast(half2v, __builtin_amdgcn_cvt_pkrtz(a, b));
}

__device__ __forceinline__ half8 repack2(float4v lo, float4v hi) {
    half8 r;
#pragma unroll
    for (int j = 0; j < 2; ++j) {
        half2v a = cvt_pk(lo[2 * j], lo[2 * j + 1]);
        half2v sa = a * (_Float16)0.01f;
        half2v ma = __builtin_elementwise_max(a, sa);
        r[2 * j] = ma[0]; r[2 * j + 1] = ma[1];
        half2v b = cvt_pk(hi[2 * j], hi[2 * j + 1]);
        half2v sb = b * (_Float16)0.01f;
        half2v mb = __builtin_elementwise_max(b, sb);
        r[4 + 2 * j] = mb[0]; r[4 + 2 * j + 1] = mb[1];
    }
    return r;
}

// eidx prefetch: (src,dst) node index pair for this lane's edge of a tile
__device__ __forceinline__ int2 load_eidx(const int* __restrict__ eidx,
                                          int nE, int tile, int n)
{
    int e = tile * 16 + n;
    int ec = e < nE ? e : nE - 1;
    return make_int2(eidx[ec], eidx[nE + ec]);
}

// R2-style consume gather from prefetched indices: lane (q,n) loads chunk q
// of edge n's 4 lines. Requests HIT L1/L2 (warmed iterations earlier).
__device__ __forceinline__ void gather_tile(const _Float16* __restrict__ xs,
                                            const _Float16* __restrict__ xd,
                                            int2 sd, int q, int4* G)
{
    const char* rs = (const char*)(xs + (size_t)sd.x * 64);
    const char* rd = (const char*)(xd + (size_t)sd.y * 64);
    G[0] = *(const int4*)(rs + 16 * q);
    G[1] = *(const int4*)(rs + 64 + 16 * q);
    G[2] = *(const int4*)(rd + 16 * q);
    G[3] = *(const int4*)(rd + 64 + 16 * q);
}

// warm pass from prefetched indices: lane (c=q, n) touches line (edge n,
// combo c) once -> 64 distinct lines per instruction, one 64B fill each.
__device__ __forceinline__ int4 warm_tile(const _Float16* __restrict__ xs,
                                          const _Float16* __restrict__ xd,
                                          int2 sd, int c)
{
    int idx = (c & 2) ? sd.y : sd.x;
    const char* base = (const char*)(((c & 2) ? xd : xs) + (size_t)idx * 64);
    return *(const int4*)(base + (c & 1) * 64);
}

__global__ __launch_bounds__(256, 2)
void edge_mlp_mfma(const unsigned char* __restrict__ ws,
                   const _Float16* __restrict__ xs, const _Float16* __restrict__ xd,
                   const int* __restrict__ eidx,
                   const float* __restrict__ eb4p, const float* __restrict__ wb4p,
                   float* __restrict__ out, int nE, int ntiles)
{
    __shared__ unsigned char lds[LDS_TOTAL];
    // stride-8 pairing: blocks 16k+j and 16k+8+j (j<8) run the same tiles for
    // m=0/1 -> same XCD (%8 preserved) and adjacent dispatch -> L2 dedup.
    const int m = (blockIdx.x >> 3) & 1;
    const int bid = (blockIdx.x & 7) | ((blockIdx.x >> 4) << 3);
    const unsigned char* wbase = ws + m * MLP_W_BYTES;
    const unsigned char* rbase = ws + WS_REST_OFF + m * MLP_R_BYTES;
    {
        const uint4* s = (const uint4*)(wbase + W1F);
        uint4* d = (uint4*)lds;
        for (int i = threadIdx.x; i < LDS_TOTAL / 16; i += 256) d[i] = s[i];
    }

    const int lane = threadIdx.x & 63;
    const int q = lane >> 4, n = lane & 15;
    const int wid = (bid << 2) | (threadIdx.x >> 6);
    const int nwaves = gridDim.x << 1;     // (grid/2 blocks per MLP) * 4 waves
    const float b4s = m ? wb4p[0] : eb4p[0];
    float* __restrict__ outm = out + (m ? nE : 0);

    // ---- persistent register weights ----
    // w1a: frags (t*4+s) for s=0,1 -> 8 x half8 = 32 AGPRs (new in R17)
    half8 w1a[8];
#pragma unroll
    for (int t = 0; t < 4; ++t) {
#pragma unroll
        for (int s = 0; s < 2; ++s)
            w1a[t * 2 + s] = *(const half8*)(wbase + W1F + ((t * 4 + s) * 64 + lane) * 16);
    }
    half8 w2f[8], w3f[4];
#pragma unroll
    for (int f = 0; f < 8; ++f)
        w2f[f] = *(const half8*)(wbase + W2F + (f * 64 + lane) * 16);
#pragma unroll
    for (int f = 0; f < 4; ++f)
        w3f[f] = *(const half8*)(wbase + W3F + (f * 64 + lane) * 16);
    float4v w40 = *(const float4v*)(rbase + 0 + lane * 32);
    float4v w41 = *(const float4v*)(rbase + 0 + lane * 32 + 16);
    float4v b1f[4], b2f[4], b3f[2];
#pragma unroll
    for (int t = 0; t < 4; ++t)
        b1f[t] = *(const float4v*)(rbase + 2048 + (t * 64 + lane) * 16);
#pragma unroll
    for (int t = 0; t < 4; ++t)
        b2f[t] = *(const float4v*)(rbase + 6144 + (t * 64 + lane) * 16);
#pragma unroll
    for (int t = 0; t < 2; ++t)
        b3f[t] = *(const float4v*)(rbase + 10240 + (t * 64 + lane) * 16);

    __syncthreads();

    int4 Gcur[4];
    int4 W0 = {0,0,0,0}, W1 = {0,0,0,0}, W2 = {0,0,0,0}, junk = {0,0,0,0};
    int2 I1 = {0,0}, I2 = {0,0}, I3 = {0,0};

    int tile = wid;
    if (tile < ntiles) {
        int t1 = tile + nwaves;     if (t1 >= ntiles) t1 = ntiles - 1;
        int t2 = tile + 2 * nwaves; if (t2 >= ntiles) t2 = ntiles - 1;
        int t3 = tile + 3 * nwaves; if (t3 >= ntiles) t3 = ntiles - 1;
        int2 I0 = load_eidx(eidx, nE, tile, n);
        I1 = load_eidx(eidx, nE, t1, n);
        I2 = load_eidx(eidx, nE, t2, n);
        I3 = load_eidx(eidx, nE, t3, n);
        W0 = warm_tile(xs, xd, I0, q);
        W1 = warm_tile(xs, xd, I1, q);
        W2 = warm_tile(xs, xd, I2, q);
        gather_tile(xs, xd, I0, q, Gcur);
    }

#pragma unroll 1
    for (; tile < ntiles; tile += nwaves) {
        half8 B1[4];
#pragma unroll
        for (int s = 0; s < 4; ++s) B1[s] = __builtin_bit_cast(half8, Gcur[s]);

        // ---- layer 1: 128 -> 64. s=0,1 from AGPR (no lgkmcnt), s=2,3 from
        // LDS (reads hide behind the AGPR MFMAs). s-order preserved. ----
        __builtin_amdgcn_s_setprio(1);
        float4v acc[4];
#pragma unroll
        for (int t = 0; t < 4; ++t) {
            acc[t] = b1f[t];
            acc[t] = __builtin_amdgcn_mfma_f32_16x16x32_f16(w1a[t * 2 + 0], B1[0], acc[t], 0, 0, 0);
            acc[t] = __builtin_amdgcn_mfma_f32_16x16x32_f16(w1a[t * 2 + 1], B1[1], acc[t], 0, 0, 0);
#pragma unroll
            for (int s = 2; s < 4; ++s) {
                half8 A = *(const half8*)(lds + W1F + ((t * 4 + s) * 64 + lane) * 16);
                acc[t] = __builtin_amdgcn_mfma_f32_16x16x32_f16(A, B1[s], acc[t], 0, 0, 0);
            }
        }
        __builtin_amdgcn_s_setprio(0);

        // memory-issue block (low prio: let the other wave's compute run):
        // Gcur is dead (B1 consumed) -> gather NEXT tile into it in place.
        // Lines warmed 3 iterations ago -> L1/L2 hits; result consumed at
        // next loop top -> covered by layers 2-4 (~2K cyc >> 120cy).
        gather_tile(xs, xd, I1, q, Gcur);

        // fold oldest warm (3 iters old -> complete), rotate, issue new warm
        junk.x ^= W0.x; junk.y ^= W0.y; junk.z ^= W0.z; junk.w ^= W0.w;
        W0 = W1; W1 = W2;
        W2 = warm_tile(xs, xd, I3, q);

        // rotate eidx pipeline; issue fetch for tile+4nw
        {
            int t4 = tile + 4 * nwaves; if (t4 >= ntiles) t4 = ntiles - 1;
            I1 = I2; I2 = I3;
            I3 = load_eidx(eidx, nE, t4, n);
        }

        // ---- layers 2-4 (A from AGPR regs; high prio) ----
        __builtin_amdgcn_s_setprio(1);
        half8 B2[2] = { repack2(acc[0], acc[2]), repack2(acc[1], acc[3]) };
        float4v acc2[4];
#pragma unroll
        for (int t = 0; t < 4; ++t) {
            acc2[t] = b2f[t];
#pragma unroll
            for (int s = 0; s < 2; ++s)
                acc2[t] = __builtin_amdgcn_mfma_f32_16x16x32_f16(w2f[t * 2 + s], B2[s], acc2[t], 0, 0, 0);
        }
        half8 B3[2] = { repack2(acc2[0], acc2[2]), repack2(acc2[1], acc2[3]) };
        float4v acc3[2];
#pragma unroll
        for (int t = 0; t < 2; ++t) {
            acc3[t] = b3f[t];
#pragma unroll
            for (int s = 0; s < 2; ++s)
                acc3[t] = __builtin_amdgcn_mfma_f32_16x16x32_f16(w3f[t * 2 + s], B3[s], acc3[t], 0, 0, 0);
        }
        float o = 0.f;
#pragma unroll
        for (int r = 0; r < 4; ++r) o = fmaf(lrelu(acc3[0][r]), w40[r], o);
#pragma unroll
        for (int r = 0; r < 4; ++r) o = fmaf(lrelu(acc3[1][r]), w41[r], o);
        o += __shfl_xor(o, 16, 64);
        o += __shfl_xor(o, 32, 64);
        __builtin_amdgcn_s_setprio(0);

        int e = tile * 16 + n;
        if (q == 0 && e < nE)
            outm[e] = o + b4s;
    }

    // consume warm registers (never-taken, data-dependent guard defeats DCE)
    junk.x ^= W0.x ^ W1.x ^ W2.x;
    junk.y ^= W0.y ^ W1.y ^ W2.y;
    junk.z ^= W0.z ^ W1.z ^ W2.z;
    junk.w ^= W0.w ^ W1.w ^ W2.w;
    if (nE < 0 && (junk.x | junk.y | junk.z | junk.w) != 0)
        out[0] = -1.0f;
}

extern "C" void kernel_launch(void* const* d_in, const int* in_sizes, int n_in,
                              void* d_out, int out_size, void* d_ws, size_t ws_size,
                              hipStream_t stream)
{
    const float* x_src = (const float*)d_in[0];
    const float* x_dst = (const float*)d_in[1];
    const int*   eidx  = (const int*)d_in[2];
    const float* ew1 = (const float*)d_in[3];
    const float* eb1 = (const float*)d_in[4];
    const float* ww1 = (const float*)d_in[5];
    const float* wb1 = (const float*)d_in[6];
    const float* ew2 = (const float*)d_in[7];
    const float* eb2 = (const float*)d_in[8];
    const float* ww2 = (const float*)d_in[9];
    const float* wb2 = (const float*)d_in[10];
    const float* ew3 = (const float*)d_in[11];
    const float* eb3 = (const float*)d_in[12];
    const float* ww3 = (const float*)d_in[13];
    const float* wb3 = (const float*)d_in[14];
    const float* ew4 = (const float*)d_in[15];
    const float* eb4 = (const float*)d_in[16];
    const float* ww4 = (const float*)d_in[17];
    const float* wb4 = (const float*)d_in[18];
    float* out = (float*)d_out;

    const int nE = in_sizes[2] / 2;          // 2 x E index array (int32)
    const int nNodeElems = in_sizes[0];      // N_NODES * 64
    unsigned char* ws = (unsigned char*)d_ws;
    _Float16* xs16 = (_Float16*)(ws + WS_X16_OFF);
    _Float16* xd16 = xs16 + nNodeElems;

    prep_frags<<<68, 256, 0, stream>>>(ew1, eb1, ew2, eb2, ew3, eb3, ew4,
                                       ws, ws + WS_REST_OFF);
    prep_frags<<<68, 256, 0, stream>>>(ww1, wb1, ww2, wb2, ww3, wb3, ww4,
                                       ws + MLP_W_BYTES, ws + WS_REST_OFF + MLP_R_BYTES);
    prep_nodes<<<1024, 256, 0, stream>>>(x_src, x_dst, xs16, xd16, nNodeElems / 4);

    const int ntiles = (nE + 15) / 16;
    edge_mlp_mfma<<<1024, 256, 0, stream>>>(ws, xs16, xd16, eidx, eb4, wb4,
                                            out, nE, ntiles);
}

// Round 12
// 269.079 us; speedup vs baseline: 1.4555x; 1.0584x over previous
//
#include <hip/hip_runtime.h>

// RegressorHybrid: per-edge 2x MLP (128->64->64->32->1, lrelu 0.01), E=2M, H=64.
// Round 18: skewed software pipeline. R17 (w1 half-AGPR) = R16 exactly ->
// LDS-pipe NOT binding (R10: 40->16 reads -11%; R17: 16->8 reads 0%). The
// ~40% idle (VALU 35 + MFMA 25 = 60% combined) is the per-wave serial layer
// chain at 2 waves/SIMD. Fix: skew by one layer - each iteration interleaves
// layer1(tile t+1) [16 MFMA, LDS-fed, independent] with layers2-4(tile t)
// [repack VALU + 12 AGPR MFMA] in ONE basic block; the list scheduler fills
// each phase's dependency gaps with the other phase's ops. Extra state vs
// R16: one accumulator set (accN, 16 regs) - NOT R13/R14's full 2-tile
// doubling (those spilled at est. 212-240; audits run ~40 light). Headroom
// bought back: b1f/b2f/b3f evicted AGPR->LDS (-40 persistent; marginal LDS
// reads proven free by R17), R17's no-op w1a dropped. Unified ~ arch 135 +
// AGPR 56 (w2f/w3f/w4) ~= 190 - real margin. Warm pipeline depth 2 (W0/W1):
// warm still leads its gather by 2 iterations (~15K cyc >> 900cy fill).
// Kept: in-place gather (Gcur dead after B1 cast), setprio(1) compute /
// 0 memory, eidx I1-I3 rotating prefetch, packed cvt_pkrtz repack, stride-8
// block pairing (m=(bid>>3)&1) for L2 warm dedup, warm law R1-R5 (one warm
// b128 covers the tile's 64 lines; consume gathers hit L1/L2; FETCH 185MB
// = raw), launch_bounds(256,2) (honest alloc).
// MFMA layouts: A[m=lane&15][k=(lane>>4)*8+j], B[k=(lane>>4)*8+j][n=lane&15],
//               C/D[row=4*(lane>>4)+reg][col=lane&15].

typedef _Float16 half8  __attribute__((ext_vector_type(8)));
typedef _Float16 half4v __attribute__((ext_vector_type(4)));
typedef _Float16 half2v __attribute__((ext_vector_type(2)));
typedef float    float4v __attribute__((ext_vector_type(4)));

#define MLP_W_BYTES 28672          // w1f 16384 + w2f 8192 + w3f 4096
#define MLP_R_BYTES 12288          // w4f 2048 + b1f 4096 + b2f 4096 + b3f 2048
#define W1F 0
#define W2F 16384
#define W3F 24576
#define LB1F 16384                 // LDS offsets for biases
#define LB2F 20480
#define LB3F 24576
#define LDS_TOTAL 26624            // w1f 16384 + b1f 4096 + b2f 4096 + b3f 2048
#define WS_REST_OFF 57344
#define WS_X16_OFF  81920

__device__ __forceinline__ float lrelu(float x) { return fmaxf(x, 0.01f * x); }

__device__ __forceinline__ int uperm(int k) {
    return 16 * (2 * ((k >> 2) & 1) + ((k >> 5) & 1)) + 4 * ((k >> 3) & 3) + (k & 3);
}

// ---- pack one MLP's weights/biases into per-lane fragment order ----
__global__ void prep_frags(const float* __restrict__ w1, const float* __restrict__ b1,
                           const float* __restrict__ w2, const float* __restrict__ b2,
                           const float* __restrict__ w3, const float* __restrict__ b3,
                           const float* __restrict__ w4,
                           unsigned char* __restrict__ dstL,
                           unsigned char* __restrict__ dstR)
{
    int idx = blockIdx.x * blockDim.x + threadIdx.x;
    if (idx < 8192) {                      // w1f: [16 frags][64 lanes][8 f16]
        int L = (idx >> 3) & 63, j = idx & 7, f = idx >> 9;
        int q = L >> 4, mm = L & 15, t = f >> 2, s = f & 3;
        int k = 32 * s + 8 * q + j;
        ((_Float16*)(dstL + W1F))[idx] = (_Float16)w1[k * 64 + 16 * t + mm];
        return;
    }
    idx -= 8192;
    if (idx < 4096) {                      // w2f: [8][64][8]
        int L = (idx >> 3) & 63, j = idx & 7, f = idx >> 9;
        int q = L >> 4, mm = L & 15, t = f >> 1, s = f & 1;
        int u = uperm(32 * s + 8 * q + j);
        ((_Float16*)(dstL + W2F))[idx] = (_Float16)w2[u * 64 + 16 * t + mm];
        return;
    }
    idx -= 4096;
    if (idx < 2048) {                      // w3f: [4][64][8]
        int L = (idx >> 3) & 63, j = idx & 7, f = idx >> 9;
        int q = L >> 4, mm = L & 15, t = f >> 1, s = f & 1;
        int u = uperm(32 * s + 8 * q + j);
        ((_Float16*)(dstL + W3F))[idx] = (_Float16)w3[u * 32 + 16 * t + mm];
        return;
    }
    idx -= 2048;
    if (idx < 512) {                       // w4f
        int L = idx >> 3, j = idx & 7;
        int q = L >> 4, t = j >> 2, r = j & 3;
        ((float*)(dstR + 0))[idx] = w4[16 * t + 4 * q + r];
        return;
    }
    idx -= 512;
    if (idx < 1024) {                      // b1f
        int t = idx >> 8, L = (idx >> 2) & 63, r = idx & 3, q = L >> 4;
        ((float*)(dstR + 2048))[idx] = b1[16 * t + 4 * q + r];
        return;
    }
    idx -= 1024;
    if (idx < 1024) {                      // b2f
        int t = idx >> 8, L = (idx >> 2) & 63, r = idx & 3, q = L >> 4;
        ((float*)(dstR + 6144))[idx] = b2[16 * t + 4 * q + r];
        return;
    }
    idx -= 1024;
    if (idx < 512) {                       // b3f
        int t = idx >> 8, L = (idx >> 2) & 63, r = idx & 3, q = L >> 4;
        ((float*)(dstR + 10240))[idx] = b3[16 * t + 4 * q + r];
        return;
    }
}

// ---- convert node tables fp32 -> f16 ----
__global__ void prep_nodes(const float* __restrict__ xs, const float* __restrict__ xd,
                           _Float16* __restrict__ os, _Float16* __restrict__ od, int n4)
{
    int stride = gridDim.x * blockDim.x;
    for (int i = blockIdx.x * blockDim.x + threadIdx.x; i < n4; i += stride) {
        float4v a = ((const float4v*)xs)[i];
        float4v b = ((const float4v*)xd)[i];
        half4v ha, hb;
#pragma unroll
        for (int j = 0; j < 4; ++j) { ha[j] = (_Float16)a[j]; hb[j] = (_Float16)b[j]; }
        ((half4v*)os)[i] = ha;
        ((half4v*)od)[i] = hb;
    }
}

// packed repack: cvt_pkrtz (2 f32 -> 2 f16) then lrelu in f16 (pk mul+max).
__device__ __forceinline__ half2v cvt_pk(float a, float b) {
    return __builtin_bit_cast(half2v, __builtin_amdgcn_cvt_pkrtz(a, b));
}

__device__ __forceinline__ half8 repack2(float4v lo, float4v hi) {
    half8 r;
#pragma unroll
    for (int j = 0; j < 2; ++j) {
        half2v a = cvt_pk(lo[2 * j], lo[2 * j + 1]);
        half2v sa = a * (_Float16)0.01f;
        half2v ma = __builtin_elementwise_max(a, sa);
        r[2 * j] = ma[0]; r[2 * j + 1] = ma[1];
        half2v b = cvt_pk(hi[2 * j], hi[2 * j + 1]);
        half2v sb = b * (_Float16)0.01f;
        half2v mb = __builtin_elementwise_max(b, sb);
        r[4 + 2 * j] = mb[0]; r[4 + 2 * j + 1] = mb[1];
    }
    return r;
}

// eidx prefetch: (src,dst) node index pair for this lane's edge of a tile
// (index clamp inside handles all overshoot)
__device__ __forceinline__ int2 load_eidx(const int* __restrict__ eidx,
                                          int nE, int tile, int n)
{
    int e = tile * 16 + n;
    int ec = e < nE ? e : nE - 1;
    return make_int2(eidx[ec], eidx[nE + ec]);
}

// R2-style consume gather from prefetched indices: lane (q,n) loads chunk q
// of edge n's 4 lines. Requests HIT L1/L2 (warmed iterations earlier).
__device__ __forceinline__ void gather_tile(const _Float16* __restrict__ xs,
                                            const _Float16* __restrict__ xd,
                                            int2 sd, int q, int4* G)
{
    const char* rs = (const char*)(xs + (size_t)sd.x * 64);
    const char* rd = (const char*)(xd + (size_t)sd.y * 64);
    G[0] = *(const int4*)(rs + 16 * q);
    G[1] = *(const int4*)(rs + 64 + 16 * q);
    G[2] = *(const int4*)(rd + 16 * q);
    G[3] = *(const int4*)(rd + 64 + 16 * q);
}

// warm pass from prefetched indices: lane (c=q, n) touches line (edge n,
// combo c) once -> 64 distinct lines per instruction, one 64B fill each.
__device__ __forceinline__ int4 warm_tile(const _Float16* __restrict__ xs,
                                          const _Float16* __restrict__ xd,
                                          int2 sd, int c)
{
    int idx = (c & 2) ? sd.y : sd.x;
    const char* base = (const char*)(((c & 2) ? xd : xs) + (size_t)idx * 64);
    return *(const int4*)(base + (c & 1) * 64);
}

__global__ __launch_bounds__(256, 2)
void edge_mlp_mfma(const unsigned char* __restrict__ ws,
                   const _Float16* __restrict__ xs, const _Float16* __restrict__ xd,
                   const int* __restrict__ eidx,
                   const float* __restrict__ eb4p, const float* __restrict__ wb4p,
                   float* __restrict__ out, int nE, int ntiles)
{
    __shared__ unsigned char lds[LDS_TOTAL];
    // stride-8 pairing: blocks 16k+j and 16k+8+j (j<8) run the same tiles for
    // m=0/1 -> same XCD (%8 preserved) and adjacent dispatch -> L2 dedup.
    const int m = (blockIdx.x >> 3) & 1;
    const int bid = (blockIdx.x & 7) | ((blockIdx.x >> 4) << 3);
    const unsigned char* wbase = ws + m * MLP_W_BYTES;
    const unsigned char* rbase = ws + WS_REST_OFF + m * MLP_R_BYTES;
    {
        const uint4* s = (const uint4*)(wbase + W1F);
        uint4* d = (uint4*)lds;
        for (int i = threadIdx.x; i < 1024; i += 256) d[i] = s[i];
        const uint4* sb = (const uint4*)(rbase + 2048);     // b1f|b2f|b3f contiguous
        uint4* db = (uint4*)(lds + LB1F);
        for (int i = threadIdx.x; i < 640; i += 256) db[i] = sb[i];
    }

    const int lane = threadIdx.x & 63;
    const int q = lane >> 4, n = lane & 15;
    const int wid = (bid << 2) | (threadIdx.x >> 6);
    const int nwaves = gridDim.x << 1;     // (grid/2 blocks per MLP) * 4 waves
    const float b4s = m ? wb4p[0] : eb4p[0];
    float* __restrict__ outm = out + (m ? nE : 0);

    // ---- persistent register weights: w2f, w3f, w4 only (56 AGPRs) ----
    half8 w2f[8], w3f[4];
#pragma unroll
    for (int f = 0; f < 8; ++f)
        w2f[f] = *(const half8*)(wbase + W2F + (f * 64 + lane) * 16);
#pragma unroll
    for (int f = 0; f < 4; ++f)
        w3f[f] = *(const half8*)(wbase + W3F + (f * 64 + lane) * 16);
    float4v w40 = *(const float4v*)(rbase + 0 + lane * 32);
    float4v w41 = *(const float4v*)(rbase + 0 + lane * 32 + 16);

    __syncthreads();

    int4 Gcur[4];
    int4 W0 = {0,0,0,0}, W1 = {0,0,0,0}, junk = {0,0,0,0};
    int2 I1 = {0,0}, I2 = {0,0}, I3 = {0,0};
    float4v accP[4];

    int tile = wid;
    if (tile < ntiles) {
        int2 I0 = load_eidx(eidx, nE, tile, n);
        I1 = load_eidx(eidx, nE, tile + nwaves, n);
        I2 = load_eidx(eidx, nE, tile + 2 * nwaves, n);
        I3 = load_eidx(eidx, nE, tile + 3 * nwaves, n);
        // warm tiles t, t+1 (folded immediately; gathers queue behind fills)
        int4 ja = warm_tile(xs, xd, I0, q);
        int4 jb = warm_tile(xs, xd, I1, q);
        junk.x ^= ja.x ^ jb.x; junk.y ^= ja.y ^ jb.y;
        junk.z ^= ja.z ^ jb.z; junk.w ^= ja.w ^ jb.w;
        W0 = warm_tile(xs, xd, I2, q);
        W1 = warm_tile(xs, xd, I3, q);
        gather_tile(xs, xd, I0, q, Gcur);

        // ---- skew prologue: layer 1 for the first tile ----
        half8 B1[4];
#pragma unroll
        for (int s = 0; s < 4; ++s) B1[s] = __builtin_bit_cast(half8, Gcur[s]);
#pragma unroll
        for (int t = 0; t < 4; ++t) {
            accP[t] = *(const float4v*)(lds + LB1F + (t * 64 + lane) * 16);
#pragma unroll
            for (int s = 0; s < 4; ++s) {
                half8 A = *(const half8*)(lds + W1F + ((t * 4 + s) * 64 + lane) * 16);
                accP[t] = __builtin_amdgcn_mfma_f32_16x16x32_f16(A, B1[s], accP[t], 0, 0, 0);
            }
        }
        gather_tile(xs, xd, I1, q, Gcur);            // tile+1
        I1 = I2; I2 = I3;
        I3 = load_eidx(eidx, nE, tile + 4 * nwaves, n);
    }

#pragma unroll 1
    for (; tile < ntiles; tile += nwaves) {
        // B-operand for tile t+1 (gathered last iteration into Gcur)
        half8 B1n[4];
#pragma unroll
        for (int s = 0; s < 4; ++s) B1n[s] = __builtin_bit_cast(half8, Gcur[s]);

        __builtin_amdgcn_s_setprio(1);
        // ---- layer 1 of tile t+1 (independent of accP; scheduler fills
        //      layers-2-4 dependency gaps with these 16 MFMAs) ----
        float4v accN[4];
#pragma unroll
        for (int t = 0; t < 4; ++t) {
            accN[t] = *(const float4v*)(lds + LB1F + (t * 64 + lane) * 16);
#pragma unroll
            for (int s = 0; s < 4; ++s) {
                half8 A = *(const half8*)(lds + W1F + ((t * 4 + s) * 64 + lane) * 16);
                accN[t] = __builtin_amdgcn_mfma_f32_16x16x32_f16(A, B1n[s], accN[t], 0, 0, 0);
            }
        }

        // ---- layers 2-4 of tile t (from accP) ----
        half8 B2[2] = { repack2(accP[0], accP[2]), repack2(accP[1], accP[3]) };
        float4v acc2[4];
#pragma unroll
        for (int t = 0; t < 4; ++t) {
            acc2[t] = *(const float4v*)(lds + LB2F + (t * 64 + lane) * 16);
#pragma unroll
            for (int s = 0; s < 2; ++s)
                acc2[t] = __builtin_amdgcn_mfma_f32_16x16x32_f16(w2f[t * 2 + s], B2[s], acc2[t], 0, 0, 0);
        }
        half8 B3[2] = { repack2(acc2[0], acc2[2]), repack2(acc2[1], acc2[3]) };
        float4v acc3[2];
#pragma unroll
        for (int t = 0; t < 2; ++t) {
            acc3[t] = *(const float4v*)(lds + LB3F + (t * 64 + lane) * 16);
#pragma unroll
            for (int s = 0; s < 2; ++s)
                acc3[t] = __builtin_amdgcn_mfma_f32_16x16x32_f16(w3f[t * 2 + s], B3[s], acc3[t], 0, 0, 0);
        }
        float o = 0.f;
#pragma unroll
        for (int r = 0; r < 4; ++r) o = fmaf(lrelu(acc3[0][r]), w40[r], o);
#pragma unroll
        for (int r = 0; r < 4; ++r) o = fmaf(lrelu(acc3[1][r]), w41[r], o);
        o += __shfl_xor(o, 16, 64);
        o += __shfl_xor(o, 32, 64);
        __builtin_amdgcn_s_setprio(0);

        // ---- memory-issue block (low prio) ----
        // Gcur dead (B1n cast) -> gather tile t+2 in place; lines warmed
        // 2 iterations ago (~15K cyc >> 900cy fill) -> L1/L2 hits.
        gather_tile(xs, xd, I1, q, Gcur);
        // fold warm(t+2) (issued 2 iters ago), shift, issue warm(t+4)
        junk.x ^= W0.x; junk.y ^= W0.y; junk.z ^= W0.z; junk.w ^= W0.w;
        W0 = W1;
        W1 = warm_tile(xs, xd, I3, q);
        // rotate eidx; fetch idx(t+5)
        I1 = I2; I2 = I3;
        I3 = load_eidx(eidx, nE, tile + 5 * nwaves, n);

        int e = tile * 16 + n;
        if (q == 0 && e < nE)
            outm[e] = o + b4s;

#pragma unroll
        for (int t = 0; t < 4; ++t) accP[t] = accN[t];
    }

    // consume warm registers (never-taken, data-dependent guard defeats DCE)
    junk.x ^= W0.x ^ W1.x;
    junk.y ^= W0.y ^ W1.y;
    junk.z ^= W0.z ^ W1.z;
    junk.w ^= W0.w ^ W1.w;
    if (nE < 0 && (junk.x | junk.y | junk.z | junk.w) != 0)
        out[0] = -1.0f;
}

extern "C" void kernel_launch(void* const* d_in, const int* in_sizes, int n_in,
                              void* d_out, int out_size, void* d_ws, size_t ws_size,
                              hipStream_t stream)
{
    const float* x_src = (const float*)d_in[0];
    const float* x_dst = (const float*)d_in[1];
    const int*   eidx  = (const int*)d_in[2];
    const float* ew1 = (const float*)d_in[3];
    const float* eb1 = (const float*)d_in[4];
    const float* ww1 = (const float*)d_in[5];
    const float* wb1 = (const float*)d_in[6];
    const float* ew2 = (const float*)d_in[7];
    const float* eb2 = (const float*)d_in[8];
    const float* ww2 = (const float*)d_in[9];
    const float* wb2 = (const float*)d_in[10];
    const float* ew3 = (const float*)d_in[11];
    const float* eb3 = (const float*)d_in[12];
    const float* ww3 = (const float*)d_in[13];
    const float* wb3 = (const float*)d_in[14];
    const float* ew4 = (const float*)d_in[15];
    const float* eb4 = (const float*)d_in[16];
    const float* ww4 = (const float*)d_in[17];
    const float* wb4 = (const float*)d_in[18];
    float* out = (float*)d_out;

    const int nE = in_sizes[2] / 2;          // 2 x E index array (int32)
    const int nNodeElems = in_sizes[0];      // N_NODES * 64
    unsigned char* ws = (unsigned char*)d_ws;
    _Float16* xs16 = (_Float16*)(ws + WS_X16_OFF);
    _Float16* xd16 = xs16 + nNodeElems;

    prep_frags<<<68, 256, 0, stream>>>(ew1, eb1, ew2, eb2, ew3, eb3, ew4,
                                       ws, ws + WS_REST_OFF);
    prep_frags<<<68, 256, 0, stream>>>(ww1, wb1, ww2, wb2, ww3, wb3, ww4,
                                       ws + MLP_W_BYTES, ws + WS_REST_OFF + MLP_R_BYTES);
    prep_nodes<<<1024, 256, 0, stream>>>(x_src, x_dst, xs16, xd16, nNodeElems / 4);

    const int ntiles = (nE + 15) / 16;
    edge_mlp_mfma<<<1024, 256, 0, stream>>>(ws, xs16, xd16, eidx, eb4, wb4,
                                            out, nE, ntiles);
}